// Round 11
// baseline (154.666 us; speedup 1.0000x reference)
//
#include <hip/hip_runtime.h>

#define NPOS (4*16*64*64)             // 262144 positions
#define KCODES 512
#define CDIM 64
#define OUT_SCALAR_IDX ((size_t)NPOS * CDIM)

// d_ws layout
#define WS_MASK  0                    // 16 * uint used-code bitmask
#define WS_FCNT  64                   // 1 * int finish counter
#define WS_EMB   4096                 // 32 KB: fp8(-512*e), kg-major [kg][code][16B]
#define WS_EE    (4096 + 32768)       // 512 * float: 256*(1 + ||e||^2)

typedef float f32x4 __attribute__((ext_vector_type(4)));
typedef long lng2 __attribute__((ext_vector_type(2)));

// ---- prep: codebook -> kg-major fp8 image + biased/scaled ee + zero mask/cnt ----
__global__ __launch_bounds__(64) void vq_prep(
    const float* __restrict__ emb, char* __restrict__ ws) {
  const int r = blockIdx.x * 64 + threadIdx.x;     // 8 x 64 = 512 rows
  if (r < 17) ((int*)(ws + WS_MASK))[r] = 0;       // 16 mask words + fcnt
  float c[CDIM];
  float ee = 0.f;
  #pragma unroll
  for (int q = 0; q < 16; ++q) {
    float4 x = ((const float4*)(emb + r * CDIM))[q];
    c[4*q+0] = x.x; c[4*q+1] = x.y; c[4*q+2] = x.z; c[4*q+3] = x.w;
    ee = fmaf(x.x, x.x, ee); ee = fmaf(x.y, x.y, ee);
    ee = fmaf(x.z, x.z, ee); ee = fmaf(x.w, x.w, ee);
  }
  #pragma unroll
  for (int kg = 0; kg < 4; ++kg) {
    uint u[4];
    #pragma unroll
    for (int h = 0; h < 2; ++h)
      #pragma unroll
      for (int jj = 0; jj < 2; ++jj) {
        const int kb = h * 32 + kg * 8 + jj * 4;
        uint p = __builtin_amdgcn_cvt_pk_fp8_f32(-512.f * c[kb+0], -512.f * c[kb+1], 0u, false);
        p = __builtin_amdgcn_cvt_pk_fp8_f32(-512.f * c[kb+2], -512.f * c[kb+3], p, true);
        u[h * 2 + jj] = p;
      }
    *(uint4*)(ws + WS_EMB + kg * 8192 + r * 16) = make_uint4(u[0], u[1], u[2], u[3]);
  }
  ((float*)(ws + WS_EE))[r] = 256.f * (1.f + ee);  // bias -> acc ~256, uint-monotone
}

__global__ __launch_bounds__(512, 4) void vq_mfma(
    const float* __restrict__ z, const float* __restrict__ emb,
    char* __restrict__ ws, float* __restrict__ out) {
  __shared__ lng2 embs[2048];              // 32 KB fp8 image
  __shared__ float s_ee[KCODES];           // 2 KB
  __shared__ uint s_idx[512];              // 2 KB
  __shared__ uint s_mask[16];
  __shared__ int s_red[16];
  __shared__ int s_last;

  const int tid = threadIdx.x;
  const int lane = tid & 63;
  const int w = tid >> 6;                  // 8 waves, 16 pos per wave per chunk
  const int col = lane & 15;
  const int kg = lane >> 4;

  if (tid < 16) s_mask[tid] = 0;

  // ---- DMA first (oldest VMEM): image + ee -> LDS ----
  if (tid < 128)
    __builtin_amdgcn_global_load_lds(
        (const __attribute__((address_space(1))) void*)(ws + WS_EE + tid * 16),
        (__attribute__((address_space(3))) void*)((char*)s_ee + tid * 16), 16, 0, 0);
  const char* src = ws + WS_EMB;
  #pragma unroll
  for (int i = 0; i < 4; ++i) {
    const int off = (i * 512 + tid) * 16;
    __builtin_amdgcn_global_load_lds(
        (const __attribute__((address_space(1))) void*)(src + off),
        (__attribute__((address_space(3))) void*)((char*)embs + off), 16, 0, 0);
  }

  const int nb = blockIdx.x * 512;               // 512 positions per block
  const int b = nb >> 16, spb = nb & 65535;      // single batch per block
  const float* zp = z + ((size_t)b << 22) + spb + w * 16 + col;
  const int lbyte = kg * 8192 + col * 16;        // kg-major region base

  float pf0[16], pf1[16];
  long afx, afy;

#define ISSUE(PF, C)                                                           \
  _Pragma("unroll") for (int h = 0; h < 2; ++h)                                \
  _Pragma("unroll") for (int j = 0; j < 8; ++j)                                \
    PF[h*8+j] = zp[(C)*128 + ((size_t)(h*32 + kg*8 + j) << 16)];

#define CONV(PF)                                                               \
  {                                                                            \
    uint u0 = __builtin_amdgcn_cvt_pk_fp8_f32(PF[0], PF[1], 0u, false);        \
    u0 = __builtin_amdgcn_cvt_pk_fp8_f32(PF[2], PF[3], u0, true);              \
    uint u1 = __builtin_amdgcn_cvt_pk_fp8_f32(PF[4], PF[5], 0u, false);        \
    u1 = __builtin_amdgcn_cvt_pk_fp8_f32(PF[6], PF[7], u1, true);              \
    afx = ((long)u1 << 32) | (long)u0;                                         \
    u0 = __builtin_amdgcn_cvt_pk_fp8_f32(PF[8], PF[9], 0u, false);             \
    u0 = __builtin_amdgcn_cvt_pk_fp8_f32(PF[10], PF[11], u0, true);            \
    u1 = __builtin_amdgcn_cvt_pk_fp8_f32(PF[12], PF[13], 0u, false);           \
    u1 = __builtin_amdgcn_cvt_pk_fp8_f32(PF[14], PF[15], u1, true);            \
    afy = ((long)u1 << 32) | (long)u0;                                         \
  }

#define HOT(C)                                                                 \
  {                                                                            \
    uint key[4] = {0xFFFFFFFFu, 0xFFFFFFFFu, 0xFFFFFFFFu, 0xFFFFFFFFu};        \
    lng2 bb = *(const lng2*)((const char*)embs + lbyte);                       \
    float eev = s_ee[col];                                                     \
    _Pragma("unroll 8")                                                        \
    for (int ct = 0; ct < 32; ++ct) {                                          \
      const lng2 bc = bb;                                                      \
      const float ec = eev;                                                    \
      const uint ctv = (uint)ct;                                               \
      const int nct = (ct + 1) & 31;                                           \
      bb = *(const lng2*)((const char*)embs + nct * 256 + lbyte);              \
      eev = s_ee[nct * 16 + col];                                              \
      const f32x4 cin = {ec, ec, ec, ec};                                      \
      f32x4 acc = __builtin_amdgcn_mfma_f32_16x16x32_fp8_fp8(afx, bc.x, cin, 0, 0, 0); \
      acc = __builtin_amdgcn_mfma_f32_16x16x32_fp8_fp8(afy, bc.y, acc, 0, 0, 0); \
      _Pragma("unroll") for (int s = 0; s < 4; ++s) {                          \
        uint kb = (__builtin_bit_cast(uint, acc[s]) & 0xFFFFFFE0u) | ctv;      \
        key[s] = kb < key[s] ? kb : key[s];                                    \
      }                                                                        \
    }                                                                          \
    _Pragma("unroll") for (int s = 0; s < 4; ++s) {                            \
      uint k = (key[s] << 4) | (uint)col;                                      \
      _Pragma("unroll") for (int m = 1; m < 16; m <<= 1) {                     \
        uint o = (uint)__shfl_xor((int)k, m, 64);                              \
        k = o < k ? o : k;                                                     \
      }                                                                        \
      if (col == 0) s_idx[(C) * 128 + w * 16 + kg * 4 + s] = k;                \
    }                                                                          \
  }

  // ---- 4-chunk JIT pipeline: issue c0,c1; convert0; issue c2; barrier ----
  ISSUE(pf0, 0)
  ISSUE(pf1, 1)
  CONV(pf0)                       // compiler waits chunk0 (vmcnt<=16)
  ISSUE(pf0, 2)

  asm volatile("s_waitcnt vmcnt(32) lgkmcnt(0)" ::: "memory");  // DMA drained
  __builtin_amdgcn_sched_barrier(0);
  __builtin_amdgcn_s_barrier();
  __builtin_amdgcn_sched_barrier(0);

  HOT(0)
  CONV(pf1)                       // waits chunk1 (c2 in flight)
  ISSUE(pf1, 3)
  HOT(1)
  CONV(pf0)                       // waits chunk2 (c3 in flight)
  HOT(2)
  CONV(pf1)                       // waits chunk3
  HOT(3)

  __syncthreads();                // all 512 s_idx ready

  // ---- batched epilogue: exact fp32 gather + 2KB-segment strided write ----
  const uint kk = s_idx[tid];
  const int myidx = (int)(((kk >> 4) & 31u) * 16u + (kk & 15u));
  atomicOr(&s_mask[myidx >> 5], 1u << (myidx & 31));
  {
    const float4* ef = (const float4*)(emb + myidx * CDIM);
    float* o = out + ((size_t)b << 22) + spb + tid;
    #pragma unroll
    for (int q = 0; q < 16; ++q) {
      float4 e4 = ef[q];
      o[(size_t)(4 * q + 0) << 16] = e4.x;
      o[(size_t)(4 * q + 1) << 16] = e4.y;
      o[(size_t)(4 * q + 2) << 16] = e4.z;
      o[(size_t)(4 * q + 3) << 16] = e4.w;
    }
  }
  __syncthreads();

  // ---- used-code mask -> global (device-scope atomics, XCD-coherent) ----
  uint* gmask = (uint*)(ws + WS_MASK);
  if (tid < 16 && s_mask[tid]) atomicOr(&gmask[tid], s_mask[tid]);
  __threadfence();
  __syncthreads();
  if (tid == 0)
    s_last = (atomicAdd((int*)(ws + WS_FCNT), 1) == (int)gridDim.x - 1);
  __syncthreads();
  if (s_last) {                   // last block computes the unique count
    __threadfence();
    if (tid < 16) s_red[tid] = __popc(atomicOr(&gmask[tid], 0u));
    __syncthreads();
    if (tid == 0) {
      int c = 0;
      #pragma unroll
      for (int i = 0; i < 16; ++i) c += s_red[i];
      out[OUT_SCALAR_IDX] = (float)c;
    }
  }
}

extern "C" void kernel_launch(void* const* d_in, const int* in_sizes, int n_in,
                              void* d_out, int out_size, void* d_ws, size_t ws_size,
                              hipStream_t stream) {
  const float* z = (const float*)d_in[0];
  const float* emb = (const float*)d_in[1];
  float* out = (float*)d_out;
  char* ws = (char*)d_ws;

  vq_prep<<<8, 64, 0, stream>>>(emb, ws);
  vq_mfma<<<NPOS / 512, 512, 0, stream>>>(z, emb, ws, out);
}

// Round 12
// 39.641 us; speedup vs baseline: 3.9016x; 3.9016x over previous
//
#include <hip/hip_runtime.h>

#define NPOS (4*16*64*64)             // 262144 positions
#define KCODES 512
#define CDIM 64
#define OUT_SCALAR_IDX ((size_t)NPOS * CDIM)

// d_ws layout
#define WS_GCOUNT 0                   // 512 * int (used-flags)
#define WS_EMB    4096                // 32 KB: fp8(-512*e), kg-major [kg][code][16B]
#define WS_EE     (4096 + 32768)      // 512 * float: 256*(1 + ||e||^2)

typedef float f32x4 __attribute__((ext_vector_type(4)));
typedef long lng2 __attribute__((ext_vector_type(2)));

// ---- prep: codebook -> kg-major fp8 image + biased/scaled ee + zero flags ----
__global__ __launch_bounds__(64) void vq_prep(
    const float* __restrict__ emb, char* __restrict__ ws) {
  const int r = blockIdx.x * 64 + threadIdx.x;     // 8 x 64 = 512 rows
  ((int*)(ws + WS_GCOUNT))[r] = 0;
  float c[CDIM];
  float ee = 0.f;
  #pragma unroll
  for (int q = 0; q < 16; ++q) {
    float4 x = ((const float4*)(emb + r * CDIM))[q];
    c[4*q+0] = x.x; c[4*q+1] = x.y; c[4*q+2] = x.z; c[4*q+3] = x.w;
    ee = fmaf(x.x, x.x, ee); ee = fmaf(x.y, x.y, ee);
    ee = fmaf(x.z, x.z, ee); ee = fmaf(x.w, x.w, ee);
  }
  #pragma unroll
  for (int kg = 0; kg < 4; ++kg) {
    uint u[4];
    #pragma unroll
    for (int h = 0; h < 2; ++h)
      #pragma unroll
      for (int jj = 0; jj < 2; ++jj) {
        const int kb = h * 32 + kg * 8 + jj * 4;
        uint p = __builtin_amdgcn_cvt_pk_fp8_f32(-512.f * c[kb+0], -512.f * c[kb+1], 0u, false);
        p = __builtin_amdgcn_cvt_pk_fp8_f32(-512.f * c[kb+2], -512.f * c[kb+3], p, true);
        u[h * 2 + jj] = p;
      }
    *(uint4*)(ws + WS_EMB + kg * 8192 + r * 16) = make_uint4(u[0], u[1], u[2], u[3]);
  }
  ((float*)(ws + WS_EE))[r] = 256.f * (1.f + ee);  // bias -> acc ~256, uint-monotone
}

__global__ __launch_bounds__(512, 4) void vq_mfma(
    const float* __restrict__ z, const float* __restrict__ emb,
    const char* __restrict__ ws, float* __restrict__ out,
    int* __restrict__ gflags) {
  __shared__ lng2 embs[2048];              // 32 KB fp8 image
  __shared__ float s_ee[KCODES];           // 2 KB
  __shared__ uint s_idx[512];              // 2 KB
  __shared__ int s_hist[KCODES];           // 2 KB

  const int tid = threadIdx.x;
  const int lane = tid & 63;
  const int w = tid >> 6;                  // 8 waves, 16 pos per wave per chunk
  const int col = lane & 15;
  const int kg = lane >> 4;

  // ---- DMA first (oldest VMEM): image + ee -> LDS ----
  if (tid < 128)
    __builtin_amdgcn_global_load_lds(
        (const __attribute__((address_space(1))) void*)(ws + WS_EE + tid * 16),
        (__attribute__((address_space(3))) void*)((char*)s_ee + tid * 16), 16, 0, 0);
  const char* src = ws + WS_EMB;
  #pragma unroll
  for (int i = 0; i < 4; ++i) {
    const int off = (i * 512 + tid) * 16;
    __builtin_amdgcn_global_load_lds(
        (const __attribute__((address_space(1))) void*)(src + off),
        (__attribute__((address_space(3))) void*)((char*)embs + off), 16, 0, 0);
  }

  const int nb = blockIdx.x * 512;               // 512 positions per block
  const int b = nb >> 16, spb = nb & 65535;      // single batch per block
  const float* zp = z + ((size_t)b << 22) + spb + w * 16 + col;
  const int lbyte = kg * 8192 + col * 16;        // kg-major region base

  float pf0[16], pf1[16];
  long afx, afy;

#define ISSUE(PF, C)                                                           \
  _Pragma("unroll") for (int h = 0; h < 2; ++h)                                \
  _Pragma("unroll") for (int j = 0; j < 8; ++j)                                \
    PF[h*8+j] = zp[(C)*128 + ((size_t)(h*32 + kg*8 + j) << 16)];

#define CONV(PF)                                                               \
  {                                                                            \
    uint u0 = __builtin_amdgcn_cvt_pk_fp8_f32(PF[0], PF[1], 0u, false);        \
    u0 = __builtin_amdgcn_cvt_pk_fp8_f32(PF[2], PF[3], u0, true);              \
    uint u1 = __builtin_amdgcn_cvt_pk_fp8_f32(PF[4], PF[5], 0u, false);        \
    u1 = __builtin_amdgcn_cvt_pk_fp8_f32(PF[6], PF[7], u1, true);              \
    afx = ((long)u1 << 32) | (long)u0;                                         \
    u0 = __builtin_amdgcn_cvt_pk_fp8_f32(PF[8], PF[9], 0u, false);             \
    u0 = __builtin_amdgcn_cvt_pk_fp8_f32(PF[10], PF[11], u0, true);            \
    u1 = __builtin_amdgcn_cvt_pk_fp8_f32(PF[12], PF[13], 0u, false);           \
    u1 = __builtin_amdgcn_cvt_pk_fp8_f32(PF[14], PF[15], u1, true);            \
    afy = ((long)u1 << 32) | (long)u0;                                         \
  }

#define HOT(C)                                                                 \
  {                                                                            \
    uint key[4] = {0xFFFFFFFFu, 0xFFFFFFFFu, 0xFFFFFFFFu, 0xFFFFFFFFu};        \
    lng2 bb = *(const lng2*)((const char*)embs + lbyte);                       \
    float eev = s_ee[col];                                                     \
    _Pragma("unroll 8")                                                        \
    for (int ct = 0; ct < 32; ++ct) {                                          \
      const lng2 bc = bb;                                                      \
      const float ec = eev;                                                    \
      const uint ctv = (uint)ct;                                               \
      const int nct = (ct + 1) & 31;                                           \
      bb = *(const lng2*)((const char*)embs + nct * 256 + lbyte);              \
      eev = s_ee[nct * 16 + col];                                              \
      const f32x4 cin = {ec, ec, ec, ec};                                      \
      f32x4 acc = __builtin_amdgcn_mfma_f32_16x16x32_fp8_fp8(afx, bc.x, cin, 0, 0, 0); \
      acc = __builtin_amdgcn_mfma_f32_16x16x32_fp8_fp8(afy, bc.y, acc, 0, 0, 0); \
      _Pragma("unroll") for (int s = 0; s < 4; ++s) {                          \
        uint kb = (__builtin_bit_cast(uint, acc[s]) & 0xFFFFFFE0u) | ctv;      \
        key[s] = kb < key[s] ? kb : key[s];                                    \
      }                                                                        \
    }                                                                          \
    _Pragma("unroll") for (int s = 0; s < 4; ++s) {                            \
      uint k = (key[s] << 4) | (uint)col;                                      \
      _Pragma("unroll") for (int m = 1; m < 16; m <<= 1) {                     \
        uint o = (uint)__shfl_xor((int)k, m, 64);                              \
        k = o < k ? o : k;                                                     \
      }                                                                        \
      if (col == 0) s_idx[(C) * 128 + w * 16 + kg * 4 + s] = k;                \
    }                                                                          \
  }

  // ---- 4-chunk JIT pipeline: issue c0,c1; convert0; issue c2; barrier ----
  ISSUE(pf0, 0)
  ISSUE(pf1, 1)
  CONV(pf0)                       // compiler waits chunk0
  ISSUE(pf0, 2)
  s_hist[tid] = 0;

  asm volatile("s_waitcnt vmcnt(32) lgkmcnt(0)" ::: "memory");  // DMA drained
  __builtin_amdgcn_sched_barrier(0);
  __builtin_amdgcn_s_barrier();
  __builtin_amdgcn_sched_barrier(0);

  HOT(0)
  CONV(pf1)                       // waits chunk1 (c2 in flight)
  ISSUE(pf1, 3)
  HOT(1)
  CONV(pf0)                       // waits chunk2 (c3 in flight)
  HOT(2)
  CONV(pf1)                       // waits chunk3
  HOT(3)

  __syncthreads();                // all 512 s_idx ready

  // ---- batched epilogue: exact fp32 gather + 2KB-segment strided write ----
  const uint kk = s_idx[tid];
  const int myidx = (int)(((kk >> 4) & 31u) * 16u + (kk & 15u));
  atomicAdd(&s_hist[myidx], 1);
  {
    const float4* ef = (const float4*)(emb + myidx * CDIM);
    float* o = out + ((size_t)b << 22) + spb + tid;
    #pragma unroll
    for (int q = 0; q < 16; ++q) {
      float4 e4 = ef[q];
      o[(size_t)(4 * q + 0) << 16] = e4.x;
      o[(size_t)(4 * q + 1) << 16] = e4.y;
      o[(size_t)(4 * q + 2) << 16] = e4.z;
      o[(size_t)(4 * q + 3) << 16] = e4.w;
    }
  }
  __syncthreads();
  if (s_hist[tid]) gflags[tid] = 1;          // idempotent used-flags
}

__global__ __launch_bounds__(512) void vq_count(
    const int* __restrict__ gflags, float* __restrict__ out) {
  __shared__ int red[512];
  const int t = threadIdx.x;
  red[t] = (gflags[t] > 0) ? 1 : 0;
  __syncthreads();
  for (int s = 256; s > 0; s >>= 1) {
    if (t < s) red[t] += red[t + s];
    __syncthreads();
  }
  if (t == 0) out[OUT_SCALAR_IDX] = (float)red[0];
}

extern "C" void kernel_launch(void* const* d_in, const int* in_sizes, int n_in,
                              void* d_out, int out_size, void* d_ws, size_t ws_size,
                              hipStream_t stream) {
  const float* z = (const float*)d_in[0];
  const float* emb = (const float*)d_in[1];
  float* out = (float*)d_out;
  char* ws = (char*)d_ws;
  int* gflags = (int*)(ws + WS_GCOUNT);

  vq_prep<<<8, 64, 0, stream>>>(emb, ws);
  vq_mfma<<<NPOS / 512, 512, 0, stream>>>(z, emb, ws, out, gflags);
  vq_count<<<1, 512, 0, stream>>>(gflags, out);
}

// Round 13
// 38.747 us; speedup vs baseline: 3.9917x; 1.0231x over previous
//
#include <hip/hip_runtime.h>

#define NPOS (4*16*64*64)             // 262144 positions
#define KCODES 512
#define CDIM 64
#define OUT_SCALAR_IDX ((size_t)NPOS * CDIM)

// d_ws layout
#define WS_GCOUNT 0                   // 512 * int (used-flags)
#define WS_EMB    4096                // 32 KB: fp8(-512*e), kg-major [kg][code][16B]
#define WS_EE     (4096 + 32768)      // 512 * float: 256*(1 + ||e||^2)

typedef float f32x4 __attribute__((ext_vector_type(4)));
typedef long lng2 __attribute__((ext_vector_type(2)));

// ---- prep: codebook -> kg-major fp8 image + biased/scaled ee + zero flags ----
__global__ __launch_bounds__(64) void vq_prep(
    const float* __restrict__ emb, char* __restrict__ ws) {
  const int r = blockIdx.x * 64 + threadIdx.x;     // 8 x 64 = 512 rows
  ((int*)(ws + WS_GCOUNT))[r] = 0;
  float c[CDIM];
  float ee = 0.f;
  #pragma unroll
  for (int q = 0; q < 16; ++q) {
    float4 x = ((const float4*)(emb + r * CDIM))[q];
    c[4*q+0] = x.x; c[4*q+1] = x.y; c[4*q+2] = x.z; c[4*q+3] = x.w;
    ee = fmaf(x.x, x.x, ee); ee = fmaf(x.y, x.y, ee);
    ee = fmaf(x.z, x.z, ee); ee = fmaf(x.w, x.w, ee);
  }
  #pragma unroll
  for (int kg = 0; kg < 4; ++kg) {
    uint u[4];
    #pragma unroll
    for (int h = 0; h < 2; ++h)
      #pragma unroll
      for (int jj = 0; jj < 2; ++jj) {
        const int kb = h * 32 + kg * 8 + jj * 4;
        uint p = __builtin_amdgcn_cvt_pk_fp8_f32(-512.f * c[kb+0], -512.f * c[kb+1], 0u, false);
        p = __builtin_amdgcn_cvt_pk_fp8_f32(-512.f * c[kb+2], -512.f * c[kb+3], p, true);
        u[h * 2 + jj] = p;
      }
    *(uint4*)(ws + WS_EMB + kg * 8192 + r * 16) = make_uint4(u[0], u[1], u[2], u[3]);
  }
  ((float*)(ws + WS_EE))[r] = 256.f * (1.f + ee);  // bias -> acc ~256, uint-monotone
}

__global__ __launch_bounds__(512, 8) void vq_mfma(
    const float* __restrict__ z, const float* __restrict__ emb,
    const char* __restrict__ ws, float* __restrict__ out,
    int* __restrict__ gflags) {
  __shared__ lng2 embs[2048];              // 32 KB fp8 image
  __shared__ float s_ee[KCODES];           // 2 KB
  __shared__ uint s_idx[256];              // 1 KB
  __shared__ int s_hist[KCODES];           // 2 KB

  const int tid = threadIdx.x;
  const int lane = tid & 63;
  const int w = tid >> 6;                  // 8 waves, 16 pos per wave per chunk
  const int col = lane & 15;
  const int kg = lane >> 4;

  // ---- DMA first (oldest VMEM): image + ee -> LDS ----
  if (tid < 128)
    __builtin_amdgcn_global_load_lds(
        (const __attribute__((address_space(1))) void*)(ws + WS_EE + tid * 16),
        (__attribute__((address_space(3))) void*)((char*)s_ee + tid * 16), 16, 0, 0);
  const char* src = ws + WS_EMB;
  #pragma unroll
  for (int i = 0; i < 4; ++i) {
    const int off = (i * 512 + tid) * 16;
    __builtin_amdgcn_global_load_lds(
        (const __attribute__((address_space(1))) void*)(src + off),
        (__attribute__((address_space(3))) void*)((char*)embs + off), 16, 0, 0);
  }

  // ---- bijective XCD swizzle: each XCD gets a contiguous 32K-position range ----
  const int swz = (blockIdx.x & 7) * 128 + (blockIdx.x >> 3);   // 1024 % 8 == 0
  const int nb = swz * 256;                      // 256 positions per block
  const int b = nb >> 16, spb = nb & 65535;      // single batch per block
  const float* zp = z + ((size_t)b << 22) + spb + w * 16 + col;
  const int lbyte = kg * 8192 + col * 16;        // kg-major region base

  float pf0[16], pf1[16];
  long afx, afy;

#define ISSUE(PF, C)                                                           \
  _Pragma("unroll") for (int h = 0; h < 2; ++h)                                \
  _Pragma("unroll") for (int j = 0; j < 8; ++j)                                \
    PF[h*8+j] = zp[(C)*128 + ((size_t)(h*32 + kg*8 + j) << 16)];

#define CONV(PF)                                                               \
  {                                                                            \
    uint u0 = __builtin_amdgcn_cvt_pk_fp8_f32(PF[0], PF[1], 0u, false);        \
    u0 = __builtin_amdgcn_cvt_pk_fp8_f32(PF[2], PF[3], u0, true);              \
    uint u1 = __builtin_amdgcn_cvt_pk_fp8_f32(PF[4], PF[5], 0u, false);        \
    u1 = __builtin_amdgcn_cvt_pk_fp8_f32(PF[6], PF[7], u1, true);              \
    afx = ((long)u1 << 32) | (long)u0;                                         \
    u0 = __builtin_amdgcn_cvt_pk_fp8_f32(PF[8], PF[9], 0u, false);             \
    u0 = __builtin_amdgcn_cvt_pk_fp8_f32(PF[10], PF[11], u0, true);            \
    u1 = __builtin_amdgcn_cvt_pk_fp8_f32(PF[12], PF[13], 0u, false);           \
    u1 = __builtin_amdgcn_cvt_pk_fp8_f32(PF[14], PF[15], u1, true);            \
    afy = ((long)u1 << 32) | (long)u0;                                         \
  }

#define HOT(C)                                                                 \
  {                                                                            \
    uint key[4] = {0xFFFFFFFFu, 0xFFFFFFFFu, 0xFFFFFFFFu, 0xFFFFFFFFu};        \
    lng2 bb = *(const lng2*)((const char*)embs + lbyte);                       \
    float eev = s_ee[col];                                                     \
    _Pragma("unroll 8")                                                        \
    for (int ct = 0; ct < 32; ++ct) {                                          \
      const lng2 bc = bb;                                                      \
      const float ec = eev;                                                    \
      const uint ctv = (uint)ct;                                               \
      const int nct = (ct + 1) & 31;                                           \
      bb = *(const lng2*)((const char*)embs + nct * 256 + lbyte);              \
      eev = s_ee[nct * 16 + col];                                              \
      const f32x4 cin = {ec, ec, ec, ec};                                      \
      f32x4 acc = __builtin_amdgcn_mfma_f32_16x16x32_fp8_fp8(afx, bc.x, cin, 0, 0, 0); \
      acc = __builtin_amdgcn_mfma_f32_16x16x32_fp8_fp8(afy, bc.y, acc, 0, 0, 0); \
      _Pragma("unroll") for (int s = 0; s < 4; ++s) {                          \
        uint kb = (__builtin_bit_cast(uint, acc[s]) & 0xFFFFFFE0u) | ctv;      \
        key[s] = kb < key[s] ? kb : key[s];                                    \
      }                                                                        \
    }                                                                          \
    _Pragma("unroll") for (int s = 0; s < 4; ++s) {                            \
      uint k = (key[s] << 4) | (uint)col;                                      \
      _Pragma("unroll") for (int m = 1; m < 16; m <<= 1) {                     \
        uint o = (uint)__shfl_xor((int)k, m, 64);                              \
        k = o < k ? o : k;                                                     \
      }                                                                        \
      if (col == 0) s_idx[(C) * 128 + w * 16 + kg * 4 + s] = k;                \
    }                                                                          \
  }

  // ---- 2-chunk JIT pipeline ----
  ISSUE(pf0, 0)
  ISSUE(pf1, 1)
  CONV(pf0)                       // compiler waits chunk0 (c1 stays in flight)
  s_hist[tid] = 0;

  // leave exactly chunk1's 16 loads outstanding -> DMA + chunk0 drained
  asm volatile("s_waitcnt vmcnt(16) lgkmcnt(0)" ::: "memory");
  __builtin_amdgcn_sched_barrier(0);
  __builtin_amdgcn_s_barrier();
  __builtin_amdgcn_sched_barrier(0);

  HOT(0)
  CONV(pf1)                       // waits chunk1
  HOT(1)

  __syncthreads();                // all 256 s_idx ready

  // ---- epilogue: 2 threads/position, exact fp32 gather + strided write ----
  const int p = tid & 255;
  const int half = tid >> 8;                 // channels [half*32, half*32+32)
  const uint kk = s_idx[p];
  const int myidx = (int)(((kk >> 4) & 31u) * 16u + (kk & 15u));
  if (half == 0) atomicAdd(&s_hist[myidx], 1);
  {
    const float4* ef = (const float4*)(emb + myidx * CDIM + half * 32);
    float* o = out + ((size_t)b << 22) + ((size_t)(half * 32) << 16) + spb + p;
    #pragma unroll
    for (int q = 0; q < 8; ++q) {
      float4 e4 = ef[q];
      o[(size_t)(4 * q + 0) << 16] = e4.x;
      o[(size_t)(4 * q + 1) << 16] = e4.y;
      o[(size_t)(4 * q + 2) << 16] = e4.z;
      o[(size_t)(4 * q + 3) << 16] = e4.w;
    }
  }
  __syncthreads();
  if (s_hist[tid]) gflags[tid] = 1;          // idempotent used-flags
}

__global__ __launch_bounds__(512) void vq_count(
    const int* __restrict__ gflags, float* __restrict__ out) {
  __shared__ int red[512];
  const int t = threadIdx.x;
  red[t] = (gflags[t] > 0) ? 1 : 0;
  __syncthreads();
  for (int s = 256; s > 0; s >>= 1) {
    if (t < s) red[t] += red[t + s];
    __syncthreads();
  }
  if (t == 0) out[OUT_SCALAR_IDX] = (float)red[0];
}

extern "C" void kernel_launch(void* const* d_in, const int* in_sizes, int n_in,
                              void* d_out, int out_size, void* d_ws, size_t ws_size,
                              hipStream_t stream) {
  const float* z = (const float*)d_in[0];
  const float* emb = (const float*)d_in[1];
  float* out = (float*)d_out;
  char* ws = (char*)d_ws;
  int* gflags = (int*)(ws + WS_GCOUNT);

  vq_prep<<<8, 64, 0, stream>>>(emb, ws);
  vq_mfma<<<NPOS / 256, 512, 0, stream>>>(z, emb, ws, out, gflags);
  vq_count<<<1, 512, 0, stream>>>(gflags, out);
}

// Round 14
// 38.366 us; speedup vs baseline: 4.0314x; 1.0099x over previous
//
#include <hip/hip_runtime.h>

#define NPOS (4*16*64*64)             // 262144 positions
#define KCODES 512
#define CDIM 64
#define OUT_SCALAR_IDX ((size_t)NPOS * CDIM)
#define NBLK 512                      // vq_mfma grid

// d_ws layout
#define WS_EMB   0                    // 32 KB: fp8(-512*e), kg-major [kg][code][16B]
#define WS_EE    32768                // 512 * float: 256*(1 + ||e||^2)
#define WS_MASK  34816                // NBLK * 16 uint used-code masks (32 KB)

typedef float f32x4 __attribute__((ext_vector_type(4)));
typedef long lng2 __attribute__((ext_vector_type(2)));

// ---- prep: codebook -> kg-major fp8 image + biased/scaled ee ----
__global__ __launch_bounds__(64) void vq_prep(
    const float* __restrict__ emb, char* __restrict__ ws) {
  const int r = blockIdx.x * 64 + threadIdx.x;     // 8 x 64 = 512 rows
  float c[CDIM];
  float ee = 0.f;
  #pragma unroll
  for (int q = 0; q < 16; ++q) {
    float4 x = ((const float4*)(emb + r * CDIM))[q];
    c[4*q+0] = x.x; c[4*q+1] = x.y; c[4*q+2] = x.z; c[4*q+3] = x.w;
    ee = fmaf(x.x, x.x, ee); ee = fmaf(x.y, x.y, ee);
    ee = fmaf(x.z, x.z, ee); ee = fmaf(x.w, x.w, ee);
  }
  #pragma unroll
  for (int kg = 0; kg < 4; ++kg) {
    uint u[4];
    #pragma unroll
    for (int h = 0; h < 2; ++h)
      #pragma unroll
      for (int jj = 0; jj < 2; ++jj) {
        const int kb = h * 32 + kg * 8 + jj * 4;
        uint p = __builtin_amdgcn_cvt_pk_fp8_f32(-512.f * c[kb+0], -512.f * c[kb+1], 0u, false);
        p = __builtin_amdgcn_cvt_pk_fp8_f32(-512.f * c[kb+2], -512.f * c[kb+3], p, true);
        u[h * 2 + jj] = p;
      }
    *(uint4*)(ws + WS_EMB + kg * 8192 + r * 16) = make_uint4(u[0], u[1], u[2], u[3]);
  }
  ((float*)(ws + WS_EE))[r] = 256.f * (1.f + ee);  // bias -> acc ~256, uint-monotone
}

__global__ __launch_bounds__(512, 4) void vq_mfma(
    const float* __restrict__ z, const float* __restrict__ emb,
    char* __restrict__ ws, float* __restrict__ out) {
  __shared__ lng2 embs[2048];              // 32 KB fp8 image
  __shared__ float s_ee[KCODES];           // 2 KB
  __shared__ uint s_mask[16];

  const int tid = threadIdx.x;
  const int lane = tid & 63;
  const int w = tid >> 6;                  // 8 waves, 16 pos per wave per chunk
  const int col = lane & 15;
  const int kg = lane >> 4;

  if (tid < 16) s_mask[tid] = 0;

  // ---- DMA first (oldest VMEM): image + ee -> LDS ----
  if (tid < 128)
    __builtin_amdgcn_global_load_lds(
        (const __attribute__((address_space(1))) void*)(ws + WS_EE + tid * 16),
        (__attribute__((address_space(3))) void*)((char*)s_ee + tid * 16), 16, 0, 0);
  const char* src = ws + WS_EMB;
  #pragma unroll
  for (int i = 0; i < 4; ++i) {
    const int off = (i * 512 + tid) * 16;
    __builtin_amdgcn_global_load_lds(
        (const __attribute__((address_space(1))) void*)(src + off),
        (__attribute__((address_space(3))) void*)((char*)embs + off), 16, 0, 0);
  }

  // ---- bijective XCD swizzle (512 % 8 == 0) ----
  const int swz = (blockIdx.x & 7) * 64 + (blockIdx.x >> 3);
  const int nb = swz * 512;                      // 512 positions per block
  const int b = nb >> 16, spb = nb & 65535;      // single batch per block
  const float* zp = z + ((size_t)b << 22) + spb + w * 16 + col;
  const int lbyte = kg * 8192 + col * 16;        // kg-major region base

  float pf0[16], pf1[16];
  long afx, afy;
  uint kk[4];
  int idxs[4];
  float4 e4[4];

#define ISSUE(PF, C)                                                           \
  _Pragma("unroll") for (int h = 0; h < 2; ++h)                                \
  _Pragma("unroll") for (int j = 0; j < 8; ++j)                                \
    PF[h*8+j] = zp[(C)*128 + ((size_t)(h*32 + kg*8 + j) << 16)];

#define CONV(PF)                                                               \
  {                                                                            \
    uint u0 = __builtin_amdgcn_cvt_pk_fp8_f32(PF[0], PF[1], 0u, false);        \
    u0 = __builtin_amdgcn_cvt_pk_fp8_f32(PF[2], PF[3], u0, true);              \
    uint u1 = __builtin_amdgcn_cvt_pk_fp8_f32(PF[4], PF[5], 0u, false);        \
    u1 = __builtin_amdgcn_cvt_pk_fp8_f32(PF[6], PF[7], u1, true);              \
    afx = ((long)u1 << 32) | (long)u0;                                         \
    u0 = __builtin_amdgcn_cvt_pk_fp8_f32(PF[8], PF[9], 0u, false);             \
    u0 = __builtin_amdgcn_cvt_pk_fp8_f32(PF[10], PF[11], u0, true);            \
    u1 = __builtin_amdgcn_cvt_pk_fp8_f32(PF[12], PF[13], 0u, false);           \
    u1 = __builtin_amdgcn_cvt_pk_fp8_f32(PF[14], PF[15], u1, true);            \
    afy = ((long)u1 << 32) | (long)u0;                                         \
  }

#define HOT()                                                                  \
  {                                                                            \
    uint key[4] = {0xFFFFFFFFu, 0xFFFFFFFFu, 0xFFFFFFFFu, 0xFFFFFFFFu};        \
    lng2 bb = *(const lng2*)((const char*)embs + lbyte);                       \
    float eev = s_ee[col];                                                     \
    _Pragma("unroll 8")                                                        \
    for (int ct = 0; ct < 32; ++ct) {                                          \
      const lng2 bc = bb;                                                      \
      const float ec = eev;                                                    \
      const uint ctv = (uint)ct;                                               \
      const int nct = (ct + 1) & 31;                                           \
      bb = *(const lng2*)((const char*)embs + nct * 256 + lbyte);              \
      eev = s_ee[nct * 16 + col];                                              \
      const f32x4 cin = {ec, ec, ec, ec};                                      \
      f32x4 acc = __builtin_amdgcn_mfma_f32_16x16x32_fp8_fp8(afx, bc.x, cin, 0, 0, 0); \
      acc = __builtin_amdgcn_mfma_f32_16x16x32_fp8_fp8(afy, bc.y, acc, 0, 0, 0); \
      _Pragma("unroll") for (int s = 0; s < 4; ++s) {                          \
        uint kb = (__builtin_bit_cast(uint, acc[s]) & 0xFFFFFFE0u) | ctv;      \
        key[s] = kb < key[s] ? kb : key[s];                                    \
      }                                                                        \
    }                                                                          \
    _Pragma("unroll") for (int s = 0; s < 4; ++s) {                            \
      uint k = (key[s] << 4) | (uint)col;                                      \
      _Pragma("unroll") for (int m = 1; m < 16; m <<= 1) {                     \
        uint o = (uint)__shfl_xor((int)k, m, 64);                              \
        k = o < k ? o : k;                                                     \
      }                                                                        \
      kk[s] = k;              /* all lanes hold the group min */               \
    }                                                                          \
  }

#define GATHER()                                                               \
  _Pragma("unroll") for (int s = 0; s < 4; ++s) {                              \
    idxs[s] = (int)(((kk[s] >> 4) & 31u) * 16u + (kk[s] & 15u));               \
    e4[s] = ((const float4*)(emb + idxs[s] * CDIM))[col];                      \
    if (col == 0) atomicOr(&s_mask[idxs[s] >> 5], 1u << (idxs[s] & 31));       \
  }

#define STORE(C)                                                               \
  _Pragma("unroll") for (int s = 0; s < 4; ++s) {                              \
    float* o = out + ((size_t)b << 22) + ((size_t)(col * 4) << 16)             \
               + spb + (C) * 128 + w * 16 + kg * 4 + s;                        \
    o[0] = e4[s].x;                                                            \
    o[(size_t)1 << 16] = e4[s].y;                                              \
    o[(size_t)2 << 16] = e4[s].z;                                              \
    o[(size_t)3 << 16] = e4[s].w;                                              \
  }

  // ---- prologue: A c0,c1 in flight; drain only the DMA at the barrier ----
  ISSUE(pf0, 0)
  ISSUE(pf1, 1)
  asm volatile("s_waitcnt vmcnt(32) lgkmcnt(0)" ::: "memory");
  __builtin_amdgcn_sched_barrier(0);
  __builtin_amdgcn_s_barrier();
  __builtin_amdgcn_sched_barrier(0);

  // ---- rolling wave-local pipeline: no block barriers ----
  CONV(pf0)            // waits A c0 (c1 stays in flight)
  HOT()                // chunk 0 keys
  GATHER()             // issue c0 gather
  CONV(pf1)            // waits A c1 (gather c0 stays in flight)
  ISSUE(pf0, 2)        // A c2
  HOT()                // chunk 1 keys
  STORE(0)             // waits gather c0 (A c2 stays in flight)
  GATHER()             // issue c1 gather
  CONV(pf0)            // waits A c2 (gather c1 stays in flight)
  ISSUE(pf1, 3)        // A c3
  HOT()                // chunk 2 keys
  STORE(1)             // waits gather c1 (A c3 stays in flight)
  GATHER()             // issue c2 gather
  CONV(pf1)            // waits A c3
  HOT()                // chunk 3 keys
  STORE(2)
  GATHER()             // issue c3 gather
  STORE(3)

  __syncthreads();     // s_mask complete
  if (tid < 16)
    ((uint*)(ws + WS_MASK))[blockIdx.x * 16 + tid] = s_mask[tid];  // unconditional
}

__global__ __launch_bounds__(512) void vq_count(
    const char* __restrict__ ws, float* __restrict__ out) {
  __shared__ uint red[512];
  const int t = threadIdx.x;
  const uint* masks = (const uint*)(ws + WS_MASK);
  uint v = 0;
  #pragma unroll
  for (int g = 0; g < NBLK / 32; ++g)          // 16 blocks per thread-group
    v |= masks[((t >> 4) + g * 32) * 16 + (t & 15)];
  red[t] = v;
  __syncthreads();
  for (int s = 256; s >= 16; s >>= 1) {        // word-index (mod 16) preserved
    if (t < s) red[t] |= red[t + s];
    __syncthreads();
  }
  if (t == 0) {
    int c = 0;
    #pragma unroll
    for (int i = 0; i < 16; ++i) c += __popc(red[i]);
    out[OUT_SCALAR_IDX] = (float)c;
  }
}

extern "C" void kernel_launch(void* const* d_in, const int* in_sizes, int n_in,
                              void* d_out, int out_size, void* d_ws, size_t ws_size,
                              hipStream_t stream) {
  const float* z = (const float*)d_in[0];
  const float* emb = (const float*)d_in[1];
  float* out = (float*)d_out;
  char* ws = (char*)d_ws;

  vq_prep<<<8, 64, 0, stream>>>(emb, ws);
  vq_mfma<<<NBLK, 512, 0, stream>>>(z, emb, ws, out);
  vq_count<<<1, 512, 0, stream>>>(ws, out);
}

// Round 15
// 37.984 us; speedup vs baseline: 4.0719x; 1.0101x over previous
//
#include <hip/hip_runtime.h>

#define NPOS (4*16*64*64)             // 262144 positions
#define KCODES 512
#define CDIM 64
#define OUT_SCALAR_IDX ((size_t)NPOS * CDIM)
#define NBLK 512                      // vq_mfma grid

// d_ws layout
#define WS_EMB   0                    // 32 KB: fp8(-512*e), kg-major [kg][code][16B]
#define WS_EE    32768                // 512 * float: 256*(1 + ||e||^2)
#define WS_MASK  34816                // NBLK * 16 uint used-code masks (32 KB)

typedef float f32x4 __attribute__((ext_vector_type(4)));
typedef long lng2 __attribute__((ext_vector_type(2)));

// ---- prep: codebook -> kg-major fp8 image + biased/scaled ee ----
__global__ __launch_bounds__(64) void vq_prep(
    const float* __restrict__ emb, char* __restrict__ ws) {
  const int r = blockIdx.x * 64 + threadIdx.x;     // 8 x 64 = 512 rows
  float c[CDIM];
  float ee = 0.f;
  #pragma unroll
  for (int q = 0; q < 16; ++q) {
    float4 x = ((const float4*)(emb + r * CDIM))[q];
    c[4*q+0] = x.x; c[4*q+1] = x.y; c[4*q+2] = x.z; c[4*q+3] = x.w;
    ee = fmaf(x.x, x.x, ee); ee = fmaf(x.y, x.y, ee);
    ee = fmaf(x.z, x.z, ee); ee = fmaf(x.w, x.w, ee);
  }
  #pragma unroll
  for (int kg = 0; kg < 4; ++kg) {
    uint u[4];
    #pragma unroll
    for (int h = 0; h < 2; ++h)
      #pragma unroll
      for (int jj = 0; jj < 2; ++jj) {
        const int kb = h * 32 + kg * 8 + jj * 4;
        uint p = __builtin_amdgcn_cvt_pk_fp8_f32(-512.f * c[kb+0], -512.f * c[kb+1], 0u, false);
        p = __builtin_amdgcn_cvt_pk_fp8_f32(-512.f * c[kb+2], -512.f * c[kb+3], p, true);
        u[h * 2 + jj] = p;
      }
    *(uint4*)(ws + WS_EMB + kg * 8192 + r * 16) = make_uint4(u[0], u[1], u[2], u[3]);
  }
  ((float*)(ws + WS_EE))[r] = 256.f * (1.f + ee);  // bias -> acc ~256, uint-monotone
}

__global__ __launch_bounds__(512, 4) void vq_mfma(
    const float* __restrict__ z, const float* __restrict__ emb,
    char* __restrict__ ws, float* __restrict__ out) {
  __shared__ lng2 embs[2048];              // 32 KB fp8 image
  __shared__ float s_ee[KCODES];           // 2 KB
  __shared__ uint s_mask[16];

  const int tid = threadIdx.x;
  const int lane = tid & 63;
  const int w = tid >> 6;                  // 8 waves, 64 positions each
  const int col = lane & 15;
  const int kg = lane >> 4;

  if (tid < 16) s_mask[tid] = 0;

  // ---- DMA first (oldest VMEM): image + ee -> LDS ----
  if (tid < 128)
    __builtin_amdgcn_global_load_lds(
        (const __attribute__((address_space(1))) void*)(ws + WS_EE + tid * 16),
        (__attribute__((address_space(3))) void*)((char*)s_ee + tid * 16), 16, 0, 0);
  const char* src = ws + WS_EMB;
  #pragma unroll
  for (int i = 0; i < 4; ++i) {
    const int off = (i * 512 + tid) * 16;
    __builtin_amdgcn_global_load_lds(
        (const __attribute__((address_space(1))) void*)(src + off),
        (__attribute__((address_space(3))) void*)((char*)embs + off), 16, 0, 0);
  }

  // ---- bijective XCD swizzle (512 % 8 == 0) ----
  const int swz = (blockIdx.x & 7) * 64 + (blockIdx.x >> 3);
  const int nb = swz * 512;                      // 512 positions per block
  const int b = nb >> 16, spb = nb & 65535;      // single batch per block
  const float* zp = z + ((size_t)b << 22) + spb + w * 64 + col;
  const int lbyte = kg * 8192 + col * 16;        // kg-major region base

  float pf0[16], pf1[16];
  long af[4][2];                                 // 4 row-tiles x 2 K-halves, fp8
  uint key[4][4];
  float4 ge[2][4];                               // gather double-buffer
  int gidx[2][4];

#define ISSUE(PF, RT)                                                          \
  _Pragma("unroll") for (int h = 0; h < 2; ++h)                                \
  _Pragma("unroll") for (int j = 0; j < 8; ++j)                                \
    PF[h*8+j] = zp[(RT)*16 + ((size_t)(h*32 + kg*8 + j) << 16)];

#define CONV(PF, RT)                                                           \
  {                                                                            \
    uint u0 = __builtin_amdgcn_cvt_pk_fp8_f32(PF[0], PF[1], 0u, false);        \
    u0 = __builtin_amdgcn_cvt_pk_fp8_f32(PF[2], PF[3], u0, true);              \
    uint u1 = __builtin_amdgcn_cvt_pk_fp8_f32(PF[4], PF[5], 0u, false);        \
    u1 = __builtin_amdgcn_cvt_pk_fp8_f32(PF[6], PF[7], u1, true);              \
    af[RT][0] = ((long)u1 << 32) | (long)u0;                                   \
    u0 = __builtin_amdgcn_cvt_pk_fp8_f32(PF[8], PF[9], 0u, false);             \
    u0 = __builtin_amdgcn_cvt_pk_fp8_f32(PF[10], PF[11], u0, true);            \
    u1 = __builtin_amdgcn_cvt_pk_fp8_f32(PF[12], PF[13], 0u, false);           \
    u1 = __builtin_amdgcn_cvt_pk_fp8_f32(PF[14], PF[15], u1, true);            \
    af[RT][1] = ((long)u1 << 32) | (long)u0;                                   \
  }

#define GATHER(RT, GB)                                                         \
  _Pragma("unroll") for (int s = 0; s < 4; ++s) {                              \
    const int id = (int)(((key[RT][s] >> 4) & 31u) * 16u + (key[RT][s] & 15u)); \
    gidx[GB][s] = id;                                                          \
    ge[GB][s] = ((const float4*)(emb + id * CDIM))[col];                       \
    if (col == 0) atomicOr(&s_mask[id >> 5], 1u << (id & 31));                 \
  }

#define STORE(RT, GB)                                                          \
  _Pragma("unroll") for (int s = 0; s < 4; ++s) {                              \
    float* o = out + ((size_t)b << 22) + ((size_t)(col * 4) << 16)             \
               + spb + w * 64 + (RT) * 16 + kg * 4 + s;                        \
    o[0] = ge[GB][s].x;                                                        \
    o[(size_t)1 << 16] = ge[GB][s].y;                                          \
    o[(size_t)2 << 16] = ge[GB][s].z;                                          \
    o[(size_t)3 << 16] = ge[GB][s].w;                                          \
  }

  // ---- staggered A load/convert: CONV's in-order vmcnt wait drains the DMA ----
  ISSUE(pf0, 0)
  ISSUE(pf1, 1)
  CONV(pf0, 0)                    // waits rt0 -> DMA (older) also drained
  ISSUE(pf0, 2)
  CONV(pf1, 1)
  ISSUE(pf1, 3)
  CONV(pf0, 2)
  CONV(pf1, 3)

  __syncthreads();                // LDS image ready on all waves

  // ---- single HOT pass: 32 code-tiles x 4 row-tiles (8 MFMA / 1 KB LDS) ----
  #pragma unroll
  for (int rt = 0; rt < 4; ++rt)
    #pragma unroll
    for (int s = 0; s < 4; ++s) key[rt][s] = 0xFFFFFFFFu;

  {
    lng2 bb = *(const lng2*)((const char*)embs + lbyte);
    float eev = s_ee[col];
    #pragma unroll 8
    for (int ct = 0; ct < 32; ++ct) {
      const lng2 bc = bb;
      const float ec = eev;
      const uint ctv = (uint)ct;
      const int nct = (ct + 1) & 31;             // wrap: harmless reload
      bb = *(const lng2*)((const char*)embs + nct * 256 + lbyte);
      eev = s_ee[nct * 16 + col];
      const f32x4 cin = {ec, ec, ec, ec};
      #pragma unroll
      for (int rt = 0; rt < 4; ++rt) {
        f32x4 acc = __builtin_amdgcn_mfma_f32_16x16x32_fp8_fp8(af[rt][0], bc.x, cin, 0, 0, 0);
        acc = __builtin_amdgcn_mfma_f32_16x16x32_fp8_fp8(af[rt][1], bc.y, acc, 0, 0, 0);
        #pragma unroll
        for (int s = 0; s < 4; ++s) {
          uint kb = (__builtin_bit_cast(uint, acc[s]) & 0xFFFFFFE0u) | ctv;
          key[rt][s] = kb < key[rt][s] ? kb : key[rt][s];
        }
      }
    }
  }

  // ---- per-row argmin butterflies (keys -> all lanes of each 16-lane group) ----
  #pragma unroll
  for (int rt = 0; rt < 4; ++rt)
    #pragma unroll
    for (int s = 0; s < 4; ++s) {
      uint k = (key[rt][s] << 4) | (uint)col;    // (dist, ct, col) lex order
      #pragma unroll
      for (int m = 1; m < 16; m <<= 1) {
        uint o = (uint)__shfl_xor((int)k, m, 64);
        k = o < k ? o : k;
      }
      key[rt][s] = k;
    }

  // ---- rolling wave-local epilogue: gather (L2-hot) ahead of store ----
  GATHER(0, 0)
  GATHER(1, 1)
  STORE(0, 0)
  GATHER(2, 0)
  STORE(1, 1)
  GATHER(3, 1)
  STORE(2, 0)
  STORE(3, 1)

  __syncthreads();     // s_mask complete
  if (tid < 16)
    ((uint*)(ws + WS_MASK))[blockIdx.x * 16 + tid] = s_mask[tid];  // unconditional
}

__global__ __launch_bounds__(512) void vq_count(
    const char* __restrict__ ws, float* __restrict__ out) {
  __shared__ uint red[512];
  const int t = threadIdx.x;
  const uint* masks = (const uint*)(ws + WS_MASK);
  uint v = 0;
  #pragma unroll
  for (int g = 0; g < NBLK / 32; ++g)          // 16 blocks per thread-group
    v |= masks[((t >> 4) + g * 32) * 16 + (t & 15)];
  red[t] = v;
  __syncthreads();
  for (int s = 256; s >= 16; s >>= 1) {        // word-index (mod 16) preserved
    if (t < s) red[t] |= red[t + s];
    __syncthreads();
  }
  if (t == 0) {
    int c = 0;
    #pragma unroll
    for (int i = 0; i < 16; ++i) c += __popc(red[i]);
    out[OUT_SCALAR_IDX] = (float)c;
  }
}

extern "C" void kernel_launch(void* const* d_in, const int* in_sizes, int n_in,
                              void* d_out, int out_size, void* d_ws, size_t ws_size,
                              hipStream_t stream) {
  const float* z = (const float*)d_in[0];
  const float* emb = (const float*)d_in[1];
  float* out = (float*)d_out;
  char* ws = (char*)d_ws;

  vq_prep<<<8, 64, 0, stream>>>(emb, ws);
  vq_mfma<<<NBLK, 512, 0, stream>>>(z, emb, ws, out);
  vq_count<<<1, 512, 0, stream>>>(ws, out);
}

// Round 16
// 37.745 us; speedup vs baseline: 4.0977x; 1.0063x over previous
//
#include <hip/hip_runtime.h>

#define NPOS (4*16*64*64)             // 262144 positions
#define KCODES 512
#define CDIM 64
#define OUT_SCALAR_IDX ((size_t)NPOS * CDIM)
#define NBLK 512                      // vq_mfma grid

// d_ws layout
#define WS_MASK  0                    // NBLK * 16 uint used-code masks (32 KB)

typedef float f32x4 __attribute__((ext_vector_type(4)));
typedef long lng2 __attribute__((ext_vector_type(2)));

__global__ __launch_bounds__(512, 4) void vq_mfma(
    const float* __restrict__ z, const float* __restrict__ emb,
    char* __restrict__ ws, float* __restrict__ out) {
  __shared__ lng2 embs[2048];              // 32 KB fp8 image, kg-major [kg][code][16B]
  __shared__ float s_ee[KCODES];           // 2 KB: 256*(1 + ||e||^2)
  __shared__ uint s_mask[16];

  const int tid = threadIdx.x;
  const int lane = tid & 63;
  const int w = tid >> 6;                  // 8 waves, 64 positions each
  const int col = lane & 15;
  const int kg = lane >> 4;

  if (tid < 16) s_mask[tid] = 0;

  // ---- bijective XCD swizzle (512 % 8 == 0) ----
  const int swz = (blockIdx.x & 7) * 64 + (blockIdx.x >> 3);
  const int nb = swz * 512;                      // 512 positions per block
  const int b = nb >> 16, spb = nb & 65535;      // single batch per block
  const float* zp = z + ((size_t)b << 22) + spb + w * 64 + col;
  const int lbyte = kg * 8192 + col * 16;        // kg-major region base

  float pf0[16], pf1[16];
  long af[4][2];                                 // 4 row-tiles x 2 K-halves, fp8
  uint key[4][4];
  float4 ge[2][4];                               // gather double-buffer

#define ISSUE(PF, RT)                                                          \
  _Pragma("unroll") for (int h = 0; h < 2; ++h)                                \
  _Pragma("unroll") for (int j = 0; j < 8; ++j)                                \
    PF[h*8+j] = zp[(RT)*16 + ((size_t)(h*32 + kg*8 + j) << 16)];

#define CONV(PF, RT)                                                           \
  {                                                                            \
    uint u0 = __builtin_amdgcn_cvt_pk_fp8_f32(PF[0], PF[1], 0u, false);        \
    u0 = __builtin_amdgcn_cvt_pk_fp8_f32(PF[2], PF[3], u0, true);              \
    uint u1 = __builtin_amdgcn_cvt_pk_fp8_f32(PF[4], PF[5], 0u, false);        \
    u1 = __builtin_amdgcn_cvt_pk_fp8_f32(PF[6], PF[7], u1, true);              \
    af[RT][0] = ((long)u1 << 32) | (long)u0;                                   \
    u0 = __builtin_amdgcn_cvt_pk_fp8_f32(PF[8], PF[9], 0u, false);             \
    u0 = __builtin_amdgcn_cvt_pk_fp8_f32(PF[10], PF[11], u0, true);            \
    u1 = __builtin_amdgcn_cvt_pk_fp8_f32(PF[12], PF[13], 0u, false);           \
    u1 = __builtin_amdgcn_cvt_pk_fp8_f32(PF[14], PF[15], u1, true);            \
    af[RT][1] = ((long)u1 << 32) | (long)u0;                                   \
  }

#define GATHER(RT, GB)                                                         \
  _Pragma("unroll") for (int s = 0; s < 4; ++s) {                              \
    const int id = (int)(((key[RT][s] >> 4) & 31u) * 16u + (key[RT][s] & 15u)); \
    ge[GB][s] = ((const float4*)(emb + id * CDIM))[col];                       \
    if (col == 0) atomicOr(&s_mask[id >> 5], 1u << (id & 31));                 \
  }

#define STORE(RT, GB)                                                          \
  _Pragma("unroll") for (int s = 0; s < 4; ++s) {                              \
    float* o = out + ((size_t)b << 22) + ((size_t)(col * 4) << 16)             \
               + spb + w * 64 + (RT) * 16 + kg * 4 + s;                        \
    o[0] = ge[GB][s].x;                                                        \
    o[(size_t)1 << 16] = ge[GB][s].y;                                          \
    o[(size_t)2 << 16] = ge[GB][s].z;                                          \
    o[(size_t)3 << 16] = ge[GB][s].w;                                          \
  }

  // ---- in-block codebook prep: thread tid owns codebook row tid ----
  float4 er[16];
  #pragma unroll
  for (int q = 0; q < 16; ++q)                   // oldest VMEM: emb row (L2/L3-hot)
    er[q] = ((const float4*)(emb + tid * CDIM))[q];

  ISSUE(pf0, 0)                                  // A c0, c1 queue behind emb row
  ISSUE(pf1, 1)

  {                                              // waits er only (pf0/pf1 in flight)
    float ee = 0.f;
    #pragma unroll
    for (int q = 0; q < 16; ++q) {
      float4 x = er[q];
      ee = fmaf(x.x, x.x, ee); ee = fmaf(x.y, x.y, ee);
      ee = fmaf(x.z, x.z, ee); ee = fmaf(x.w, x.w, ee);
    }
    #pragma unroll
    for (int g = 0; g < 4; ++g) {                // region g: channels {g*8+j, 32+g*8+j}
      uint u[4];
      #pragma unroll
      for (int h = 0; h < 2; ++h)
        #pragma unroll
        for (int jj = 0; jj < 2; ++jj) {
          float4 x = er[(h * 32 + g * 8 + jj * 4) >> 2];
          uint p = __builtin_amdgcn_cvt_pk_fp8_f32(-512.f * x.x, -512.f * x.y, 0u, false);
          p = __builtin_amdgcn_cvt_pk_fp8_f32(-512.f * x.z, -512.f * x.w, p, true);
          u[h * 2 + jj] = p;
        }
      *(uint4*)((char*)embs + g * 8192 + tid * 16) = make_uint4(u[0], u[1], u[2], u[3]);
    }
    s_ee[tid] = 256.f * (1.f + ee);              // bias -> acc ~256, uint-monotone
  }

  // LDS image visible; A-loads stay in flight (no vmcnt drain)
  asm volatile("s_waitcnt lgkmcnt(0)" ::: "memory");
  __builtin_amdgcn_sched_barrier(0);
  __builtin_amdgcn_s_barrier();
  __builtin_amdgcn_sched_barrier(0);

  // ---- staggered A convert (in-order vmcnt waits keep later loads in flight) ----
  CONV(pf0, 0)
  ISSUE(pf0, 2)
  CONV(pf1, 1)
  ISSUE(pf1, 3)
  CONV(pf0, 2)
  CONV(pf1, 3)

  // ---- single HOT pass: 32 code-tiles x 4 row-tiles (8 MFMA / 1 KB LDS) ----
  #pragma unroll
  for (int rt = 0; rt < 4; ++rt)
    #pragma unroll
    for (int s = 0; s < 4; ++s) key[rt][s] = 0xFFFFFFFFu;

  {
    lng2 bb = *(const lng2*)((const char*)embs + lbyte);
    float eev = s_ee[col];
    #pragma unroll 8
    for (int ct = 0; ct < 32; ++ct) {
      const lng2 bc = bb;
      const float ec = eev;
      const uint ctv = (uint)ct;
      const int nct = (ct + 1) & 31;             // wrap: harmless reload
      bb = *(const lng2*)((const char*)embs + nct * 256 + lbyte);
      eev = s_ee[nct * 16 + col];
      const f32x4 cin = {ec, ec, ec, ec};
      #pragma unroll
      for (int rt = 0; rt < 4; ++rt) {
        f32x4 acc = __builtin_amdgcn_mfma_f32_16x16x32_fp8_fp8(af[rt][0], bc.x, cin, 0, 0, 0);
        acc = __builtin_amdgcn_mfma_f32_16x16x32_fp8_fp8(af[rt][1], bc.y, acc, 0, 0, 0);
        #pragma unroll
        for (int s = 0; s < 4; ++s) {
          uint kb = (__builtin_bit_cast(uint, acc[s]) & 0xFFFFFFE0u) | ctv;
          key[rt][s] = kb < key[rt][s] ? kb : key[rt][s];
        }
      }
    }
  }

  // ---- per-row argmin butterflies ----
  #pragma unroll
  for (int rt = 0; rt < 4; ++rt)
    #pragma unroll
    for (int s = 0; s < 4; ++s) {
      uint k = (key[rt][s] << 4) | (uint)col;    // (dist, ct, col) lex order
      #pragma unroll
      for (int m = 1; m < 16; m <<= 1) {
        uint o = (uint)__shfl_xor((int)k, m, 64);
        k = o < k ? o : k;
      }
      key[rt][s] = k;
    }

  // ---- rolling wave-local epilogue: gather (L2-hot) ahead of store ----
  GATHER(0, 0)
  GATHER(1, 1)
  STORE(0, 0)
  GATHER(2, 0)
  STORE(1, 1)
  GATHER(3, 1)
  STORE(2, 0)
  STORE(3, 1)

  __syncthreads();     // s_mask complete
  if (tid < 16)
    ((uint*)(ws + WS_MASK))[blockIdx.x * 16 + tid] = s_mask[tid];  // unconditional
}

__global__ __launch_bounds__(512) void vq_count(
    const char* __restrict__ ws, float* __restrict__ out) {
  __shared__ uint red[512];
  const int t = threadIdx.x;
  const uint* masks = (const uint*)(ws + WS_MASK);
  uint v = 0;
  #pragma unroll
  for (int g = 0; g < NBLK / 32; ++g)          // 16 blocks per thread-group
    v |= masks[((t >> 4) + g * 32) * 16 + (t & 15)];
  red[t] = v;
  __syncthreads();
  for (int s = 256; s >= 16; s >>= 1) {        // word-index (mod 16) preserved
    if (t < s) red[t] |= red[t + s];
    __syncthreads();
  }
  if (t == 0) {
    int c = 0;
    #pragma unroll
    for (int i = 0; i < 16; ++i) c += __popc(red[i]);
    out[OUT_SCALAR_IDX] = (float)c;
  }
}

extern "C" void kernel_launch(void* const* d_in, const int* in_sizes, int n_in,
                              void* d_out, int out_size, void* d_ws, size_t ws_size,
                              hipStream_t stream) {
  const float* z = (const float*)d_in[0];
  const float* emb = (const float*)d_in[1];
  float* out = (float*)d_out;
  char* ws = (char*)d_ws;

  vq_mfma<<<NBLK, 512, 0, stream>>>(z, emb, ws, out);
  vq_count<<<1, 512, 0, stream>>>(ws, out);
}